// Round 2
// baseline (274.962 us; speedup 1.0000x reference)
//
#include <hip/hip_runtime.h>
#include <math.h>

#define H  128
#define NB 16

// ---------------------------------------------------------------------------
// Kernel 1: g = mlp(emb) over the N unique nodes, plus per-node 1/||g||.
//   mlp(x) = elu(x @ W1^T + b1) @ W2^T + b2
// Block: 128 threads (thread t owns output column t), NB=16 nodes per block.
// ---------------------------------------------------------------------------
__global__ __launch_bounds__(128) void mlp_nodes_kernel(
    const float* __restrict__ emb,
    const float* __restrict__ W1, const float* __restrict__ b1,
    const float* __restrict__ W2, const float* __restrict__ b2,
    float* __restrict__ g, float* __restrict__ invn, int N)
{
    __shared__ float xs[NB][H];   // input rows (then reused for g^2)
    __shared__ float hs[NB][H];   // hidden rows

    const int t     = threadIdx.x;          // column index 0..127
    const int node0 = blockIdx.x * NB;

    // ---- stage NB input rows into LDS (coalesced: thread t loads col t) ----
    #pragma unroll
    for (int n = 0; n < NB; ++n) {
        if (node0 + n < N)
            xs[n][t] = emb[(size_t)(node0 + n) * H + t];
    }
    __syncthreads();

    // ---- layer 1: h[n][t] = elu(b1[t] + sum_k x[n][k] * W1[t][k]) ----
    float acc[NB];
    {
        const float bb = b1[t];
        #pragma unroll
        for (int n = 0; n < NB; ++n) acc[n] = bb;

        const float4* w1p = (const float4*)(W1 + (size_t)t * H);
        for (int k4 = 0; k4 < H / 4; ++k4) {
            const float4 w = w1p[k4];
            #pragma unroll
            for (int n = 0; n < NB; ++n) {
                const float4 x = *(const float4*)&xs[n][k4 * 4];
                acc[n] += w.x * x.x + w.y * x.y + w.z * x.z + w.w * x.w;
            }
        }
        #pragma unroll
        for (int n = 0; n < NB; ++n) {
            const float v = acc[n];
            hs[n][t] = v > 0.f ? v : (expf(v) - 1.f);   // ELU, alpha=1
        }
    }
    __syncthreads();

    // ---- layer 2: g[n][t] = b2[t] + sum_k h[n][k] * W2[t][k] ----
    {
        const float bb = b2[t];
        #pragma unroll
        for (int n = 0; n < NB; ++n) acc[n] = bb;

        const float4* w2p = (const float4*)(W2 + (size_t)t * H);
        for (int k4 = 0; k4 < H / 4; ++k4) {
            const float4 w = w2p[k4];
            #pragma unroll
            for (int n = 0; n < NB; ++n) {
                const float4 x = *(const float4*)&hs[n][k4 * 4];
                acc[n] += w.x * x.x + w.y * x.y + w.z * x.z + w.w * x.w;
            }
        }
    }

    // ---- write g (coalesced) and squared values for the norm reduction ----
    #pragma unroll
    for (int n = 0; n < NB; ++n) {
        if (node0 + n < N)
            g[(size_t)(node0 + n) * H + t] = acc[n];
    }
    __syncthreads();   // xs no longer needed as inputs
    #pragma unroll
    for (int n = 0; n < NB; ++n) xs[n][t] = acc[n] * acc[n];
    __syncthreads();

    // ---- per-node inverse norm: 16 threads each sum one row of 128 ----
    if (t < NB && node0 + t < N) {
        float s = 0.f;
        #pragma unroll 8
        for (int k = 0; k < H; ++k) s += xs[t][k];
        float nn = sqrtf(s);
        if (nn < 1e-8f) nn = 1e-8f;
        invn[node0 + t] = 1.f / nn;
    }
}

// ---------------------------------------------------------------------------
// Kernel 2: per-edge cosine similarity from precomputed g and invn.
// Half-wave (32 lanes) per edge; lane i loads float4 chunk i of both rows.
// NOTE: harness passes integer inputs as int32 (NOT int64, despite reference).
// ---------------------------------------------------------------------------
__global__ __launch_bounds__(256) void edge_kernel(
    const int* __restrict__ ei,         // [2, E] int32: col then row
    const float* __restrict__ g,
    const float* __restrict__ invn,
    float* __restrict__ out, int E)
{
    const int gid  = blockIdx.x * blockDim.x + threadIdx.x;
    const int e    = gid >> 5;          // 32 lanes per edge
    const int lane = gid & 31;
    if (e >= E) return;

    const int c = ei[e];
    const int r = ei[(size_t)e + (size_t)E];

    const float4* p1 = (const float4*)(g + (size_t)c * H);
    const float4* p2 = (const float4*)(g + (size_t)r * H);
    const float4 a = p1[lane];
    const float4 b = p2[lane];
    float s = a.x * b.x + a.y * b.y + a.z * b.z + a.w * b.w;

    #pragma unroll
    for (int off = 16; off; off >>= 1) s += __shfl_xor(s, off, 32);

    if (lane == 0) out[e] = s * invn[c] * invn[r];
}

// ---------------------------------------------------------------------------
extern "C" void kernel_launch(void* const* d_in, const int* in_sizes, int n_in,
                              void* d_out, int out_size, void* d_ws, size_t ws_size,
                              hipStream_t stream) {
    const float* emb = (const float*)d_in[0];
    const int*   ei  = (const int*)d_in[1];
    const float* W1  = (const float*)d_in[2];
    const float* b1  = (const float*)d_in[3];
    const float* W2  = (const float*)d_in[4];
    const float* b2  = (const float*)d_in[5];
    float*       out = (float*)d_out;

    const int N = in_sizes[0] / H;
    const int E = in_sizes[1] / 2;

    float* g    = (float*)d_ws;            // N*H floats
    float* invn = g + (size_t)N * H;       // N floats

    mlp_nodes_kernel<<<(N + NB - 1) / NB, 128, 0, stream>>>(
        emb, W1, b1, W2, b2, g, invn, N);

    const int threads = 256;               // 8 edges per block
    const int blocks  = (E + (threads / 32) - 1) / (threads / 32);
    edge_kernel<<<blocks, threads, 0, stream>>>(ei, g, invn, out, E);
}

// Round 3
// 141.150 us; speedup vs baseline: 1.9480x; 1.9480x over previous
//
#include <hip/hip_runtime.h>
#include <math.h>

#define H 128
#define MROWS 64           // node rows per MLP block
#define XS 136             // padded row stride (ushorts) for bf16 LDS tiles

typedef __attribute__((ext_vector_type(8))) short short8;
typedef __attribute__((ext_vector_type(4))) float floatx4;

__device__ __forceinline__ unsigned short f2bf(float f) {
    unsigned u = __float_as_uint(f);
    return (unsigned short)((u + 0x7FFFu + ((u >> 16) & 1u)) >> 16);  // RNE
}

// ---------------------------------------------------------------------------
// Kernel 0: convert W1,W2 (fp32) to bf16 once. Wbf[0..16383]=W1, [16384..]=W2
// ---------------------------------------------------------------------------
__global__ void prep_weights(const float* __restrict__ W1,
                             const float* __restrict__ W2,
                             unsigned short* __restrict__ Wbf) {
    int i = blockIdx.x * 256 + threadIdx.x;       // 32768 total
    if (i < 16384)       Wbf[i] = f2bf(W1[i]);
    else if (i < 32768)  Wbf[i] = f2bf(W2[i - 16384]);
}

// ---------------------------------------------------------------------------
// Kernel 1: ghat = normalize(mlp(emb)) in bf16, via MFMA 16x16x32 bf16.
// Block 256 threads (4 waves), 64 node rows. Wave w owns output rows 16w..16w+15.
// ---------------------------------------------------------------------------
__global__ __launch_bounds__(256, 2) void mlp_mfma(
    const float* __restrict__ emb, const unsigned short* __restrict__ Wbf,
    const float* __restrict__ b1, const float* __restrict__ b2,
    unsigned short* __restrict__ ghat, int N)
{
    __shared__ unsigned short Wl[H * XS];         // 34 KB, W1 then W2 (padded)
    __shared__ char dbuf[2 * MROWS * XS * 2];     // xs|hs (bf16, padded), then gs (fp32)
    __shared__ float invn_s[MROWS];

    unsigned short* xs = (unsigned short*)dbuf;   // [MROWS][XS]
    unsigned short* hs = xs + MROWS * XS;         // [MROWS][XS]
    float*          gs = (float*)dbuf;            // [MROWS][H] overlays xs+hs

    const int tid   = threadIdx.x;
    const int wave  = tid >> 6, lane = tid & 63;
    const int quad  = lane >> 4, l15 = lane & 15;
    const int node0 = blockIdx.x * MROWS;

    // ---- stage W1 (bf16, row-padded): 2048 chunks of 8 ushorts ----
    {
        const float4* src = (const float4*)Wbf;
        #pragma unroll
        for (int i = 0; i < 8; ++i) {
            int cc = i * 256 + tid;               // chunk id
            int row = cc >> 4, c = cc & 15;
            *(float4*)(Wl + row * XS + c * 8) = src[cc];
        }
    }
    // ---- stage x rows (fp32 -> bf16, row-padded) ----
    #pragma unroll
    for (int i = 0; i < 8; ++i) {
        int flat = i * 1024 + tid * 4;            // logical [64][128]
        int rowl = flat >> 7, col = flat & 127;
        float4 v = make_float4(0.f, 0.f, 0.f, 0.f);
        if (node0 + rowl < N)
            v = *(const float4*)(emb + (size_t)(node0 + rowl) * H + col);
        ushort4 b;
        b.x = f2bf(v.x); b.y = f2bf(v.y); b.z = f2bf(v.z); b.w = f2bf(v.w);
        *(ushort4*)(xs + rowl * XS + col) = b;
    }
    __syncthreads();

    short8 afr[4];
    const int mrow = wave * 16 + l15;

    // ---- layer 1: hs = elu(x @ W1^T + b1) ----
    #pragma unroll
    for (int ks = 0; ks < 4; ++ks)
        afr[ks] = *(const short8*)(xs + mrow * XS + ks * 32 + quad * 8);
    #pragma unroll
    for (int nt = 0; nt < 8; ++nt) {
        floatx4 acc = {0.f, 0.f, 0.f, 0.f};
        #pragma unroll
        for (int ks = 0; ks < 4; ++ks) {
            short8 bfr = *(const short8*)(Wl + (nt * 16 + l15) * XS + ks * 32 + quad * 8);
            acc = __builtin_amdgcn_mfma_f32_16x16x32_bf16(afr[ks], bfr, acc, 0, 0, 0);
        }
        const int col = nt * 16 + l15;
        const float bb = b1[col];
        #pragma unroll
        for (int r = 0; r < 4; ++r) {
            float v = acc[r] + bb;
            v = v > 0.f ? v : (__expf(v) - 1.f);  // ELU
            hs[(wave * 16 + quad * 4 + r) * XS + col] = f2bf(v);
        }
    }
    __syncthreads();                              // hs done; W1/xs reads done

    // ---- stage W2 over W1 ----
    {
        const float4* src = (const float4*)(Wbf + 16384);
        #pragma unroll
        for (int i = 0; i < 8; ++i) {
            int cc = i * 256 + tid;
            int row = cc >> 4, c = cc & 15;
            *(float4*)(Wl + row * XS + c * 8) = src[cc];
        }
    }
    __syncthreads();

    // ---- layer 2: g = h @ W2^T + b2, fused row-norm ----
    #pragma unroll
    for (int ks = 0; ks < 4; ++ks)
        afr[ks] = *(const short8*)(hs + mrow * XS + ks * 32 + quad * 8);
    __syncthreads();                              // all A-frags in regs -> gs may overwrite xs/hs

    float sq[4] = {0.f, 0.f, 0.f, 0.f};
    #pragma unroll
    for (int nt = 0; nt < 8; ++nt) {
        floatx4 acc = {0.f, 0.f, 0.f, 0.f};
        #pragma unroll
        for (int ks = 0; ks < 4; ++ks) {
            short8 bfr = *(const short8*)(Wl + (nt * 16 + l15) * XS + ks * 32 + quad * 8);
            acc = __builtin_amdgcn_mfma_f32_16x16x32_bf16(afr[ks], bfr, acc, 0, 0, 0);
        }
        const int col = nt * 16 + l15;
        const float bb = b2[col];
        #pragma unroll
        for (int r = 0; r < 4; ++r) {
            float v = acc[r] + bb;
            gs[(wave * 16 + quad * 4 + r) * H + col] = v;
            sq[r] += v * v;
        }
    }
    // per-row sum across the 16 lanes of each quad group
    #pragma unroll
    for (int r = 0; r < 4; ++r) {
        float s = sq[r];
        #pragma unroll
        for (int m = 8; m; m >>= 1) s += __shfl_xor(s, m);
        if (l15 == 0) {
            float nn = sqrtf(s);
            if (nn < 1e-8f) nn = 1e-8f;
            invn_s[wave * 16 + quad * 4 + r] = 1.f / nn;
        }
    }
    __syncthreads();

    // ---- normalized bf16 store (coalesced 8B/lane) ----
    #pragma unroll
    for (int i = 0; i < 8; ++i) {
        int flat = i * 1024 + tid * 4;
        int rowl = flat >> 7, col = flat & 127;
        if (node0 + rowl < N) {
            float4 v = *(const float4*)(gs + flat);
            float s = invn_s[rowl];
            ushort4 b;
            b.x = f2bf(v.x * s); b.y = f2bf(v.y * s);
            b.z = f2bf(v.z * s); b.w = f2bf(v.w * s);
            *(ushort4*)(ghat + (size_t)(node0 + rowl) * H + col) = b;
        }
    }
}

// ---------------------------------------------------------------------------
// Kernel 2: out[e] = ghat[col_e] . ghat[row_e]   (rows already unit-norm)
// 16 lanes per edge, 16 B (8 bf16) per lane per row.
// ---------------------------------------------------------------------------
__device__ __forceinline__ float bfdot(unsigned a, unsigned b) {
    float a0 = __uint_as_float(a << 16),        b0 = __uint_as_float(b << 16);
    float a1 = __uint_as_float(a & 0xFFFF0000u), b1 = __uint_as_float(b & 0xFFFF0000u);
    return a0 * b0 + a1 * b1;
}

__global__ __launch_bounds__(256) void edge_cos(
    const int* __restrict__ ei, const unsigned short* __restrict__ ghat,
    float* __restrict__ out, int E)
{
    const int gid = blockIdx.x * 256 + threadIdx.x;
    const int e = gid >> 4, sub = gid & 15;
    if (e >= E) return;

    const int c = ei[e];
    const int r = ei[e + E];

    const uint4 ua = *(const uint4*)(ghat + (size_t)c * H + sub * 8);
    const uint4 ub = *(const uint4*)(ghat + (size_t)r * H + sub * 8);
    float s = bfdot(ua.x, ub.x) + bfdot(ua.y, ub.y)
            + bfdot(ua.z, ub.z) + bfdot(ua.w, ub.w);

    #pragma unroll
    for (int m = 8; m; m >>= 1) s += __shfl_xor(s, m);
    if (sub == 0) out[e] = s;
}

// ---------------------------------------------------------------------------
extern "C" void kernel_launch(void* const* d_in, const int* in_sizes, int n_in,
                              void* d_out, int out_size, void* d_ws, size_t ws_size,
                              hipStream_t stream) {
    const float* emb = (const float*)d_in[0];
    const int*   ei  = (const int*)d_in[1];
    const float* W1  = (const float*)d_in[2];
    const float* W2  = (const float*)d_in[4];
    const float* b1  = (const float*)d_in[3];
    const float* b2  = (const float*)d_in[5];
    float*       out = (float*)d_out;

    const int N = in_sizes[0] / H;
    const int E = in_sizes[1] / 2;

    unsigned short* Wbf  = (unsigned short*)d_ws;       // 32768 bf16
    unsigned short* ghat = Wbf + 32768;                 // N*H bf16

    prep_weights<<<128, 256, 0, stream>>>(W1, W2, Wbf);
    mlp_mfma<<<(N + MROWS - 1) / MROWS, 256, 0, stream>>>(emb, Wbf, b1, b2, ghat, N);
    edge_cos<<<(E + 15) / 16, 256, 0, stream>>>(ei, ghat, out, E);
}

// Round 5
// 123.451 us; speedup vs baseline: 2.2273x; 1.1434x over previous
//
#include <hip/hip_runtime.h>
#include <math.h>

#define H 128
#define MROWS 64           // node rows per MLP block
#define XS 136             // padded row stride (ushorts) for bf16 LDS tiles

typedef __attribute__((ext_vector_type(8))) short short8;
typedef __attribute__((ext_vector_type(4))) float floatx4;

__device__ __forceinline__ unsigned short f2bf(float f) {
    unsigned u = __float_as_uint(f);
    return (unsigned short)((u + 0x7FFFu + ((u >> 16) & 1u)) >> 16);  // RNE
}

// ---------------------------------------------------------------------------
// Kernel 0: convert W1,W2 (fp32) to bf16 once. Wbf[0..16383]=W1, [16384..]=W2
// ---------------------------------------------------------------------------
__global__ void prep_weights(const float* __restrict__ W1,
                             const float* __restrict__ W2,
                             unsigned short* __restrict__ Wbf) {
    int i = blockIdx.x * 256 + threadIdx.x;       // 32768 total
    if (i < 16384)       Wbf[i] = f2bf(W1[i]);
    else if (i < 32768)  Wbf[i] = f2bf(W2[i - 16384]);
}

// ---------------------------------------------------------------------------
// Kernel 1: g = mlp(emb); write per-row-quantized int8 of normalize(g)
// plus per-row fp32 scale.  MFMA 16x16x32 bf16, 256 thr / 64 rows per block.
// ---------------------------------------------------------------------------
__global__ __launch_bounds__(256, 2) void mlp_mfma(
    const float* __restrict__ emb, const unsigned short* __restrict__ Wbf,
    const float* __restrict__ b1, const float* __restrict__ b2,
    signed char* __restrict__ qtab, float* __restrict__ scl, int N)
{
    __shared__ unsigned short Wl[H * XS];         // 34 KB, W1 then W2 (padded)
    __shared__ char dbuf[2 * MROWS * XS * 2];     // xs|hs (bf16), overlaid by gs (fp32)
    __shared__ float invn_s[MROWS];
    __shared__ float amax_s[MROWS];

    unsigned short* xs = (unsigned short*)dbuf;   // [MROWS][XS]
    unsigned short* hs = xs + MROWS * XS;         // [MROWS][XS]
    float*          gs = (float*)dbuf;            // [MROWS][H] overlays xs+hs

    const int tid   = threadIdx.x;
    const int wave  = tid >> 6, lane = tid & 63;
    const int quad  = lane >> 4, l15 = lane & 15;
    const int node0 = blockIdx.x * MROWS;

    // ---- stage W1 (bf16, row-padded): 2048 chunks of 8 ushorts ----
    {
        const float4* src = (const float4*)Wbf;
        #pragma unroll
        for (int i = 0; i < 8; ++i) {
            int cc = i * 256 + tid;               // chunk id
            int row = cc >> 4, c = cc & 15;
            *(float4*)(Wl + row * XS + c * 8) = src[cc];
        }
    }
    // ---- stage x rows (fp32 -> bf16, row-padded) ----
    #pragma unroll
    for (int i = 0; i < 8; ++i) {
        int flat = i * 1024 + tid * 4;            // logical [64][128]
        int rowl = flat >> 7, col = flat & 127;
        float4 v = make_float4(0.f, 0.f, 0.f, 0.f);
        if (node0 + rowl < N)
            v = *(const float4*)(emb + (size_t)(node0 + rowl) * H + col);
        ushort4 b;
        b.x = f2bf(v.x); b.y = f2bf(v.y); b.z = f2bf(v.z); b.w = f2bf(v.w);
        *(ushort4*)(xs + rowl * XS + col) = b;
    }
    __syncthreads();

    short8 afr[4];
    const int mrow = wave * 16 + l15;

    // ---- layer 1: hs = elu(x @ W1^T + b1) ----
    #pragma unroll
    for (int ks = 0; ks < 4; ++ks)
        afr[ks] = *(const short8*)(xs + mrow * XS + ks * 32 + quad * 8);
    #pragma unroll
    for (int nt = 0; nt < 8; ++nt) {
        floatx4 acc = {0.f, 0.f, 0.f, 0.f};
        #pragma unroll
        for (int ks = 0; ks < 4; ++ks) {
            short8 bfr = *(const short8*)(Wl + (nt * 16 + l15) * XS + ks * 32 + quad * 8);
            acc = __builtin_amdgcn_mfma_f32_16x16x32_bf16(afr[ks], bfr, acc, 0, 0, 0);
        }
        const int col = nt * 16 + l15;
        const float bb = b1[col];
        #pragma unroll
        for (int r = 0; r < 4; ++r) {
            float v = acc[r] + bb;
            v = v > 0.f ? v : (__expf(v) - 1.f);  // ELU
            hs[(wave * 16 + quad * 4 + r) * XS + col] = f2bf(v);
        }
    }
    __syncthreads();                              // hs done; W1/xs reads done

    // ---- stage W2 over W1 ----
    {
        const float4* src = (const float4*)(Wbf + 16384);
        #pragma unroll
        for (int i = 0; i < 8; ++i) {
            int cc = i * 256 + tid;
            int row = cc >> 4, c = cc & 15;
            *(float4*)(Wl + row * XS + c * 8) = src[cc];
        }
    }
    __syncthreads();

    // ---- layer 2: g = h @ W2^T + b2, fused row sum-sq and max-abs ----
    #pragma unroll
    for (int ks = 0; ks < 4; ++ks)
        afr[ks] = *(const short8*)(hs + mrow * XS + ks * 32 + quad * 8);
    __syncthreads();                              // A-frags in regs -> gs may overwrite xs/hs

    float sq[4] = {0.f, 0.f, 0.f, 0.f};
    float am[4] = {0.f, 0.f, 0.f, 0.f};
    #pragma unroll
    for (int nt = 0; nt < 8; ++nt) {
        floatx4 acc = {0.f, 0.f, 0.f, 0.f};
        #pragma unroll
        for (int ks = 0; ks < 4; ++ks) {
            short8 bfr = *(const short8*)(Wl + (nt * 16 + l15) * XS + ks * 32 + quad * 8);
            acc = __builtin_amdgcn_mfma_f32_16x16x32_bf16(afr[ks], bfr, acc, 0, 0, 0);
        }
        const int col = nt * 16 + l15;
        const float bb = b2[col];
        #pragma unroll
        for (int r = 0; r < 4; ++r) {
            float v = acc[r] + bb;
            gs[(wave * 16 + quad * 4 + r) * H + col] = v;
            sq[r] += v * v;
            am[r] = fmaxf(am[r], fabsf(v));
        }
    }
    // per-row reductions across the 16 lanes of each quad group
    #pragma unroll
    for (int r = 0; r < 4; ++r) {
        float s = sq[r], a = am[r];
        #pragma unroll
        for (int m = 8; m; m >>= 1) {
            s += __shfl_xor(s, m);
            a = fmaxf(a, __shfl_xor(a, m));
        }
        if (l15 == 0) {
            const int row = wave * 16 + quad * 4 + r;
            float nn = sqrtf(s);
            if (nn < 1e-8f) nn = 1e-8f;
            invn_s[row] = 1.f / nn;
            amax_s[row] = fmaxf(a, 1e-20f);
        }
    }
    __syncthreads();

    // ---- per-row scale (quant step of the normalized row) ----
    if (tid < MROWS && node0 + tid < N)
        scl[node0 + tid] = amax_s[tid] * invn_s[tid] * (1.f / 127.f);

    // ---- int8 quantized store: q = round(g * 127 / rowmax) ----
    // 64 rows x 128 int8 = 512 chunks of 16 B; 8 chunks per row.
    #pragma unroll
    for (int i = 0; i < 2; ++i) {
        int chunk = i * 256 + tid;
        int row = chunk >> 3, c0 = (chunk & 7) * 16;
        if (node0 + row < N) {
            const float qs = 127.f / amax_s[row];
            unsigned u[4];
            #pragma unroll
            for (int w = 0; w < 4; ++w) {
                unsigned pk = 0;
                #pragma unroll
                for (int j = 0; j < 4; ++j) {
                    float v = gs[row * H + c0 + w * 4 + j] * qs;
                    int q = (int)rintf(v);
                    q = q > 127 ? 127 : (q < -127 ? -127 : q);
                    pk |= ((unsigned)(q & 255)) << (8 * j);
                }
                u[w] = pk;
            }
            *(uint4*)(qtab + (size_t)(node0 + row) * H + c0) =
                make_uint4(u[0], u[1], u[2], u[3]);
        }
    }
}

// ---------------------------------------------------------------------------
// Kernel 2: out[e] = (q[col] . q[row]) * scl[col] * scl[row]
// 8 lanes per edge, 16 int8 per lane per row (128 B rows).
// ---------------------------------------------------------------------------
__device__ __forceinline__ int dot4(unsigned a, unsigned b) {
    int s = 0;
    #pragma unroll
    for (int j = 0; j < 4; ++j)
        s += (int)((signed char)(a >> (8 * j))) * (int)((signed char)(b >> (8 * j)));
    return s;
}

__global__ __launch_bounds__(256) void edge_cos(
    const int* __restrict__ ei, const signed char* __restrict__ qtab,
    const float* __restrict__ scl, float* __restrict__ out, int E)
{
    const int gid = blockIdx.x * 256 + threadIdx.x;
    const int e = gid >> 3, sub = gid & 7;
    if (e >= E) return;

    const int c = ei[e];
    const int r = ei[e + E];

    const uint4 ua = *(const uint4*)(qtab + (size_t)c * H + sub * 16);
    const uint4 ub = *(const uint4*)(qtab + (size_t)r * H + sub * 16);
    int s = dot4(ua.x, ub.x) + dot4(ua.y, ub.y)
          + dot4(ua.z, ub.z) + dot4(ua.w, ub.w);

    #pragma unroll
    for (int m = 4; m; m >>= 1) s += __shfl_xor(s, m);
    if (sub == 0) out[e] = (float)s * scl[c] * scl[r];
}

// ---------------------------------------------------------------------------
extern "C" void kernel_launch(void* const* d_in, const int* in_sizes, int n_in,
                              void* d_out, int out_size, void* d_ws, size_t ws_size,
                              hipStream_t stream) {
    const float* emb = (const float*)d_in[0];
    const int*   ei  = (const int*)d_in[1];
    const float* W1  = (const float*)d_in[2];
    const float* b1  = (const float*)d_in[3];
    const float* W2  = (const float*)d_in[4];
    const float* b2  = (const float*)d_in[5];
    float*       out = (float*)d_out;

    const int N = in_sizes[0] / H;
    const int E = in_sizes[1] / 2;

    unsigned short* Wbf  = (unsigned short*)d_ws;           // 32768 bf16 = 64 KB
    signed char*    qtab = (signed char*)(Wbf + 32768);     // N*H int8
    float*          scl  = (float*)(qtab + (size_t)N * H);  // N fp32

    prep_weights<<<128, 256, 0, stream>>>(W1, W2, Wbf);
    mlp_mfma<<<(N + MROWS - 1) / MROWS, 256, 0, stream>>>(emb, Wbf, b1, b2, qtab, scl, N);
    edge_cos<<<(E * 8 + 255) / 256, 256, 0, stream>>>(ei, qtab, scl, out, E);
}